// Round 3
// baseline (350.299 us; speedup 1.0000x reference)
//
#include <hip/hip_runtime.h>
#include <hip/hip_bf16.h>

typedef __bf16 bf16;
typedef bf16 bf16x8 __attribute__((ext_vector_type(8)));
typedef bf16 bf16x4 __attribute__((ext_vector_type(4)));
typedef short s16x4 __attribute__((ext_vector_type(4)));
typedef float f32x4 __attribute__((ext_vector_type(4)));

#define SCALE 0.17677669529663687f  // 1/sqrt(32)

// LDS (bf16 elems): xb/o [64][200] @0 ; vt per-wave [32][68] @12800+w*2176
// f32 proj-out overlay [64][200] f32 over everything (51,168B <= 51,712B)
#define OFF_V 12800
#define SMEM_ELEMS 25856   // 51,712 B -> LDS allows 3 blocks/CU

#if defined(__has_builtin)
#if __has_builtin(__builtin_amdgcn_mfma_f32_16x16x16bf16_1k)
#define HAS_MFMA16 1
#endif
#endif

// ---------------- prep kernel (unchanged from R2, passed) ----------------
__global__ void wattn_prep(const float* __restrict__ wq, const float* __restrict__ wkv,
                           const float* __restrict__ bias_table, const float* __restrict__ proj_w,
                           bf16* __restrict__ wqkvT, bf16* __restrict__ projT,
                           float* __restrict__ biasB)
{
    int t = blockIdx.x * 256 + threadIdx.x;
    if (t < 110592) {                       // wqkvT[n][k] = W[k][n]
        int n = t / 192, k = t % 192;
        float v = (n < 192) ? wq[k * 192 + n] : wkv[k * 384 + (n - 192)];
        wqkvT[t] = (bf16)v;
    } else if (t < 147456) {                // projT[n][k] = proj_w[k][n]
        int e = t - 110592;
        int n = e / 192, k = e % 192;
        projT[e] = (bf16)proj_w[k * 192 + n];
    } else if (t < 172032) {                // biasB[h][m>>2][n][m&3]
        int e = t - 147456;
        int h  = e >> 12;
        int mb = (e >> 8) & 15;
        int n  = (e >> 2) & 63;
        int mr = e & 3;
        int m  = mb * 4 + mr;
        int idx = ((n & 7) - (m & 7) + 7) * 15 + ((n >> 3) - (m >> 3) + 7);
        biasB[e] = bias_table[idx * 6 + h];
    }
}

#if !defined(HAS_MFMA16)
// fallback helper: build K=32 frag (k=8*gi+j over d/m in [0,32)) from two
// D-layout bf16x4 tiles (k=4*gi+rg per tile). 8 shuffles, no LDS.
__device__ __forceinline__ bf16x8 build8(bf16x4 t0, bf16x4 t1, int li, int gi) {
    union { bf16x4 v; unsigned u[2]; } a0, a1;
    a0.v = t0; a1.v = t1;
    int b = li + 32 * (gi & 1);
    unsigned l0  = __shfl(a0.u[0], b),      l1  = __shfl(a0.u[1], b);
    unsigned l0h = __shfl(a0.u[0], b + 16), l1h = __shfl(a0.u[1], b + 16);
    unsigned h0  = __shfl(a1.u[0], b),      h1  = __shfl(a1.u[1], b);
    unsigned h0h = __shfl(a1.u[0], b + 16), h1h = __shfl(a1.u[1], b + 16);
    bool hi = (gi & 2);
    union { bf16x8 v8; unsigned u[4]; } r;
    r.u[0] = hi ? h0 : l0;   r.u[1] = hi ? h1 : l1;
    r.u[2] = hi ? h0h : l0h; r.u[3] = hi ? h1h : l1h;
    return r.v8;
}
#endif

// ---------------- fused main kernel: one window per block, one head per wave ----------------
__global__ __launch_bounds__(384, 3)
void wattn_main(const float* __restrict__ x, const bf16* __restrict__ wqkvT,
                const float* __restrict__ bq, const float* __restrict__ bkv,
                const bf16* __restrict__ projT, const float* __restrict__ biasB,
                const float* __restrict__ proj_b, float* __restrict__ outg)
{
    __shared__ __align__(16) bf16 smem[SMEM_ELEMS];
    const int tid = threadIdx.x;
    const int li  = tid & 15;
    const int gi  = (tid >> 4) & 3;
    const int w   = tid >> 6;        // wave = head, 0..5
    const int win = blockIdx.x;

    bf16* xb = smem;                          // x -> (dead) -> attn-out [n][c]
    bf16* vt = smem + OFF_V + w * 2176;       // per-wave private v^T [32][68]

    const int srow = tid / 48, scol = tid % 48;
    const f32x4 fz = {0.f, 0.f, 0.f, 0.f};

    // ---- stage x: f32 global -> bf16 LDS [64][200] (coalesced, div-free) ----
    {
        const float4* xg = (const float4*)(x + (size_t)win * 12288);
#pragma unroll
        for (int i = 0; i < 8; ++i) {
            float4 p = xg[(srow + 8 * i) * 48 + scol];
            bf16x4 v; v[0]=(bf16)p.x; v[1]=(bf16)p.y; v[2]=(bf16)p.z; v[3]=(bf16)p.w;
            *(bf16x4*)&xb[(srow + 8 * i) * 200 + scol * 4] = v;
        }
    }
    __syncthreads();                                     // B1

    // ---- QKV^T GEMM: D[f][n] = W^T[f][k] * x^T[k][n]; wave w owns head-w features ----
    // j: 0,1 = q tiles; 2,3 = k tiles; 4,5 = v tiles (16 features each)
    f32x4 acc[6][4];
#pragma unroll
    for (int j = 0; j < 6; ++j)
#pragma unroll
        for (int c = 0; c < 4; ++c) acc[j][c] = fz;
#pragma unroll
    for (int kk = 0; kk < 6; ++kk) {
        bf16x8 bx[4], aw[6];
#pragma unroll
        for (int c = 0; c < 4; ++c)
            bx[c] = *(const bf16x8*)&xb[(c * 16 + li) * 200 + kk * 32 + gi * 8];
#pragma unroll
        for (int j = 0; j < 6; ++j) {
            int T = (j < 2) ? (2 * w + j) : (j < 4) ? (12 + 2 * w + (j - 2)) : (24 + 2 * w + (j - 4));
            aw[j] = *(const bf16x8*)&wqkvT[(size_t)(T * 16 + li) * 192 + kk * 32 + gi * 8];
        }
#pragma unroll
        for (int j = 0; j < 6; ++j)
#pragma unroll
            for (int c = 0; c < 4; ++c)
                acc[j][c] = __builtin_amdgcn_mfma_f32_16x16x32_bf16(aw[j], bx[c], acc[j][c], 0, 0, 0);
    }
    __syncthreads();                                     // B2 (all x reads done)

    // ---- epilogue: bias + leaky; q,k stay in REGISTERS; v -> private LDS transpose ----
    bf16x4 qf[2][4], kf[2][4];
    {
        float4 bb[6];
#pragma unroll
        for (int j = 0; j < 2; ++j) bb[j]     = *(const float4*)&bq [32 * w + 16 * j + 4 * gi];
#pragma unroll
        for (int j = 0; j < 2; ++j) bb[2 + j] = *(const float4*)&bkv[32 * w + 16 * j + 4 * gi];
#pragma unroll
        for (int j = 0; j < 2; ++j) bb[4 + j] = *(const float4*)&bkv[192 + 32 * w + 16 * j + 4 * gi];
#pragma unroll
        for (int j = 0; j < 6; ++j) {
            const float* bp = (const float*)&bb[j];
#pragma unroll
            for (int c = 0; c < 4; ++c) {
                bf16x4 r;
#pragma unroll
                for (int rg = 0; rg < 4; ++rg) {
                    float t = acc[j][c][rg] + bp[rg];
                    t = fmaxf(t, 0.f) + 0.2f * fminf(t, 0.f);   // leaky
                    if (j < 2) t *= SCALE;
                    r[rg] = (bf16)t;
                }
                if (j < 2)      qf[j][c] = r;
                else if (j < 4) kf[j - 2][c] = r;
                else {
                    // v^T[d][m]: d = 16*(j-4)+4*gi+rg, m = 16*c+li (per-wave private)
#pragma unroll
                    for (int rg = 0; rg < 4; ++rg)
                        vt[(16 * (j - 4) + 4 * gi + rg) * 68 + c * 16 + li] = r[rg];
                }
            }
        }
    }

    // ---- QK^T straight from registers: S^T[m][n] tiles s[cm][cn] ----
    f32x4 s[4][4];
#if defined(HAS_MFMA16)
#pragma unroll
    for (int cm = 0; cm < 4; ++cm)
#pragma unroll
        for (int cn = 0; cn < 4; ++cn) {
            f32x4 t = __builtin_amdgcn_mfma_f32_16x16x16bf16_1k(
                __builtin_bit_cast(s16x4, kf[0][cm]), __builtin_bit_cast(s16x4, qf[0][cn]), fz, 0, 0, 0);
            s[cm][cn] = __builtin_amdgcn_mfma_f32_16x16x16bf16_1k(
                __builtin_bit_cast(s16x4, kf[1][cm]), __builtin_bit_cast(s16x4, qf[1][cn]), t, 0, 0, 0);
        }
#else
    {
        bf16x8 ka[4], qb[4];
#pragma unroll
        for (int cm = 0; cm < 4; ++cm) ka[cm] = build8(kf[0][cm], kf[1][cm], li, gi);
#pragma unroll
        for (int cn = 0; cn < 4; ++cn) qb[cn] = build8(qf[0][cn], qf[1][cn], li, gi);
#pragma unroll
        for (int cm = 0; cm < 4; ++cm)
#pragma unroll
            for (int cn = 0; cn < 4; ++cn)
                s[cm][cn] = __builtin_amdgcn_mfma_f32_16x16x32_bf16(ka[cm], qb[cn], fz, 0, 0, 0);
    }
#endif

    // ---- + bias, softmax over keys (16 in-lane + shfl_xor 16/32), P -> bf16 regs ----
    float rs[4];
    bf16x4 pb[4][4];
#pragma unroll
    for (int cn = 0; cn < 4; ++cn) {
        float m_ = -1e30f;
#pragma unroll
        for (int cm = 0; cm < 4; ++cm) {
            s[cm][cn] += *(const f32x4*)&biasB[w * 4096 + (4 * cm + gi) * 256 + (16 * cn + li) * 4];
#pragma unroll
            for (int rg = 0; rg < 4; ++rg) m_ = fmaxf(m_, s[cm][cn][rg]);
        }
        m_ = fmaxf(m_, __shfl_xor(m_, 16));
        m_ = fmaxf(m_, __shfl_xor(m_, 32));
        float ss = 0.f;
#pragma unroll
        for (int cm = 0; cm < 4; ++cm) {
            bf16x4 r;
#pragma unroll
            for (int rg = 0; rg < 4; ++rg) {
                float p = __expf(s[cm][cn][rg] - m_);
                ss += p;
                r[rg] = (bf16)p;
            }
            pb[cm][cn] = r;
        }
        ss += __shfl_xor(ss, 16);
        ss += __shfl_xor(ss, 32);
        rs[cn] = 1.f / ss;
    }

    // ---- PV: out^T[d][n] = v^T (LDS A-frags) x P^T (register B-frags) ----
    f32x4 o[2][4];
#pragma unroll
    for (int dt = 0; dt < 2; ++dt) {
#if defined(HAS_MFMA16)
        s16x4 av[4];
#pragma unroll
        for (int ks = 0; ks < 4; ++ks)
            av[ks] = *(const s16x4*)&vt[(dt * 16 + li) * 68 + ks * 16 + gi * 4];
#pragma unroll
        for (int cn = 0; cn < 4; ++cn) {
            f32x4 t = fz;
#pragma unroll
            for (int ks = 0; ks < 4; ++ks)
                t = __builtin_amdgcn_mfma_f32_16x16x16bf16_1k(
                        av[ks], __builtin_bit_cast(s16x4, pb[ks][cn]), t, 0, 0, 0);
            o[dt][cn] = t;
        }
#else
        bf16x8 av2[2];
#pragma unroll
        for (int c = 0; c < 2; ++c)
            av2[c] = *(const bf16x8*)&vt[(dt * 16 + li) * 68 + c * 32 + gi * 8];
#pragma unroll
        for (int cn = 0; cn < 4; ++cn) {
            f32x4 t = fz;
#pragma unroll
            for (int c = 0; c < 2; ++c)
                t = __builtin_amdgcn_mfma_f32_16x16x32_bf16(
                        av2[c], build8(pb[2 * c][cn], pb[2 * c + 1][cn], li, gi), t, 0, 0, 0);
            o[dt][cn] = t;
        }
#endif
    }
    // normalize + write attn-out [n][c] into xb (x dead since B2)
#pragma unroll
    for (int dt = 0; dt < 2; ++dt)
#pragma unroll
        for (int cn = 0; cn < 4; ++cn) {
            bf16x4 r;
#pragma unroll
            for (int rg = 0; rg < 4; ++rg) r[rg] = (bf16)(o[dt][cn][rg] * rs[cn]);
            *(bf16x4*)&xb[(cn * 16 + li) * 200 + 32 * w + 16 * dt + 4 * gi] = r;
        }
    __syncthreads();                                     // B3 (attn-out complete)

    // ---- proj: y^T[c][n] = Wp^T (A) * o^T (B from xb) ----
    f32x4 pa[2][4];
#pragma unroll
    for (int ct = 0; ct < 2; ++ct)
#pragma unroll
        for (int cn = 0; cn < 4; ++cn) pa[ct][cn] = fz;
#pragma unroll
    for (int kk = 0; kk < 6; ++kk) {
        bf16x8 bo[4], awp[2];
#pragma unroll
        for (int cn = 0; cn < 4; ++cn)
            bo[cn] = *(const bf16x8*)&xb[(cn * 16 + li) * 200 + kk * 32 + gi * 8];
#pragma unroll
        for (int ct = 0; ct < 2; ++ct)
            awp[ct] = *(const bf16x8*)&projT[(size_t)((2 * w + ct) * 16 + li) * 192 + kk * 32 + gi * 8];
#pragma unroll
        for (int ct = 0; ct < 2; ++ct)
#pragma unroll
            for (int cn = 0; cn < 4; ++cn)
                pa[ct][cn] = __builtin_amdgcn_mfma_f32_16x16x32_bf16(awp[ct], bo[cn], pa[ct][cn], 0, 0, 0);
    }
    __syncthreads();                                     // B4 (all o reads done)

    // ---- + proj bias -> f32 overlay [64][200] over whole smem ----
    {
        float* of = (float*)smem;
#pragma unroll
        for (int ct = 0; ct < 2; ++ct) {
            float4 pbv = *(const float4*)&proj_b[32 * w + 16 * ct + 4 * gi];
#pragma unroll
            for (int cn = 0; cn < 4; ++cn) {
                f32x4 y = pa[ct][cn];
                y[0] += pbv.x; y[1] += pbv.y; y[2] += pbv.z; y[3] += pbv.w;
                *(f32x4*)&of[(cn * 16 + li) * 200 + 32 * w + 16 * ct + 4 * gi] = y;
            }
        }
    }
    __syncthreads();                                     // B5

    // ---- coalesced copy-out ----
    {
        const float* ofr = (const float*)smem;
        float4* og = (float4*)(outg + (size_t)win * 12288);
#pragma unroll
        for (int i = 0; i < 8; ++i)
            og[(srow + 8 * i) * 48 + scol] = *(const float4*)&ofr[(srow + 8 * i) * 200 + scol * 4];
    }
}

extern "C" void kernel_launch(void* const* d_in, const int* in_sizes, int n_in,
                              void* d_out, int out_size, void* d_ws, size_t ws_size,
                              hipStream_t stream)
{
    const float* x          = (const float*)d_in[0];
    const float* wq         = (const float*)d_in[1];
    const float* bq         = (const float*)d_in[2];
    const float* wkv        = (const float*)d_in[3];
    const float* bkv        = (const float*)d_in[4];
    const float* bias_table = (const float*)d_in[5];
    const float* proj_w     = (const float*)d_in[6];
    const float* proj_b     = (const float*)d_in[7];
    float* out = (float*)d_out;

    int B = in_sizes[0] / (64 * 192);

    bf16*  wqkvT = (bf16*)d_ws;
    bf16*  projT = (bf16*)((char*)d_ws + 221184);
    float* biasB = (float*)((char*)d_ws + 294912);

    wattn_prep<<<672, 256, 0, stream>>>(wq, wkv, bias_table, proj_w, wqkvT, projT, biasB);

    wattn_main<<<B, 384, 0, stream>>>(x, wqkvT, bq, bkv, projT, biasB, proj_b, out);
}